// Round 1
// baseline (8984.052 us; speedup 1.0000x reference)
//
#include <hip/hip_runtime.h>

#define D 128
#define DV 32   // float4 per row

typedef float4 f4;

// ---------------- counts ----------------
__global__ void k_count(const int* __restrict__ nm, const int* __restrict__ batch,
                        float* __restrict__ ncnt, float* __restrict__ pcnt, int M) {
    int m = blockIdx.x * 256 + threadIdx.x;
    if (m >= M) return;
    unsafeAtomicAdd(&ncnt[nm[m]], 1.0f);
    unsafeAtomicAdd(&pcnt[batch[m]], 1.0f);
}

__global__ void k_invert(float* __restrict__ v, int n) {
    int i = blockIdx.x * 256 + threadIdx.x;
    if (i < n) v[i] = 1.0f / fmaxf(v[i], 1.0f);
}

// ---------------- initial gather: h = x[nm], agg = (1+eps0)*h ----------------
__global__ void k_gather_init(const f4* __restrict__ x, const int* __restrict__ nm,
                              f4* __restrict__ h, f4* __restrict__ agg,
                              const float* __restrict__ eps, int M) {
    int idx = blockIdx.x * 256 + threadIdx.x;
    int m = idx >> 5, j = idx & 31;
    if (m >= M) return;
    f4 v = x[(size_t)nm[m] * DV + j];
    h[(size_t)m * DV + j] = v;
    float s = 1.0f + eps[0];
    agg[(size_t)m * DV + j] = make_float4(v.x * s, v.y * s, v.z * s, v.w * s);
}

// ---------------- edge scatter: agg[dst] += relu(h[src] + ea[em]) ----------------
__global__ void k_edge(const f4* __restrict__ h, const f4* __restrict__ ea,
                       const int* __restrict__ src, const int* __restrict__ dst,
                       const int* __restrict__ em, float* __restrict__ agg, int EC) {
    int idx = blockIdx.x * 256 + threadIdx.x;
    int c = idx >> 5, j = idx & 31;
    if (c >= EC) return;
    int s = src[c], d = dst[c], e = em[c];
    f4 hv = h[(size_t)s * DV + j];
    f4 ev = ea[(size_t)e * DV + j];
    float mx = fmaxf(hv.x + ev.x, 0.f), my = fmaxf(hv.y + ev.y, 0.f);
    float mz = fmaxf(hv.z + ev.z, 0.f), mw = fmaxf(hv.w + ev.w, 0.f);
    float* ap = agg + (size_t)d * D + j * 4;
    unsafeAtomicAdd(ap + 0, mx);
    unsafeAtomicAdd(ap + 1, my);
    unsafeAtomicAdd(ap + 2, mz);
    unsafeAtomicAdd(ap + 3, mw);
}

// ---------------- patch accumulate: pacc[batch[m]] += h[m] ----------------
__global__ void k_patch_accum(const f4* __restrict__ h, const int* __restrict__ batch,
                              float* __restrict__ pacc, int M) {
    int idx = blockIdx.x * 256 + threadIdx.x;
    int m = idx >> 5, j = idx & 31;
    if (m >= M) return;
    f4 v = h[(size_t)m * DV + j];
    float* pp = pacc + (size_t)batch[m] * D + j * 4;
    unsafeAtomicAdd(pp + 0, v.x);
    unsafeAtomicAdd(pp + 1, v.y);
    unsafeAtomicAdd(pp + 2, v.z);
    unsafeAtomicAdd(pp + 3, v.w);
}

// ---------------- pm_u = relu((pacc*pinv) @ W_u[l] + b_u[l]) ; [P,128] tiny GEMM ----------------
__global__ __launch_bounds__(128) void k_pmu(const float* __restrict__ pacc,
                                             const float* __restrict__ pinv,
                                             const float* __restrict__ Wu,
                                             const float* __restrict__ bu,
                                             float* __restrict__ pmu, int layer) {
    int p = blockIdx.x, c = threadIdx.x;
    const float* W = Wu + (size_t)layer * D * D;
    __shared__ float row[D];
    row[c] = pacc[(size_t)p * D + c] * pinv[p];
    __syncthreads();
    float acc = bu[layer * D + c];
#pragma unroll 8
    for (int k = 0; k < D; k++) acc += row[k] * W[(size_t)k * D + c];
    pmu[(size_t)p * D + c] = fmaxf(acc, 0.f);
}

// ---------------- h += pmu[batch[m]] ; nacc[nm[m]] += h ----------------
__global__ void k_update_node(f4* __restrict__ h, const f4* __restrict__ pmu,
                              const int* __restrict__ batch, const int* __restrict__ nm,
                              float* __restrict__ nacc, int M) {
    int idx = blockIdx.x * 256 + threadIdx.x;
    int m = idx >> 5, j = idx & 31;
    if (m >= M) return;
    f4 hv = h[(size_t)m * DV + j];
    f4 u = pmu[(size_t)batch[m] * DV + j];
    hv.x += u.x; hv.y += u.y; hv.z += u.z; hv.w += u.w;
    h[(size_t)m * DV + j] = hv;
    float* np = nacc + (size_t)nm[m] * D + j * 4;
    unsafeAtomicAdd(np + 0, hv.x);
    unsafeAtomicAdd(np + 1, hv.y);
    unsafeAtomicAdd(np + 2, hv.z);
    unsafeAtomicAdd(np + 3, hv.w);
}

// ---------------- h = nacc[nm[m]]*ninv ; agg = (1+eps[l])*h ----------------
__global__ void k_gather_mean_scale(const f4* __restrict__ nacc, const float* __restrict__ ninv,
                                    const int* __restrict__ nm, f4* __restrict__ h,
                                    f4* __restrict__ agg, const float* __restrict__ eps,
                                    int layer, int M) {
    int idx = blockIdx.x * 256 + threadIdx.x;
    int m = idx >> 5, j = idx & 31;
    if (m >= M) return;
    int n = nm[m];
    float inv = ninv[n];
    f4 v = nacc[(size_t)n * DV + j];
    v.x *= inv; v.y *= inv; v.z *= inv; v.w *= inv;
    h[(size_t)m * DV + j] = v;
    float s = 1.0f + eps[layer];
    agg[(size_t)m * DV + j] = make_float4(v.x * s, v.y * s, v.z * s, v.w * s);
}

// ---------------- GEMM: out[M,128] = A[M,128] @ W[l] + b[l] ----------------
// block: 256 threads, tile 64 rows x 64 cols, 4x4 per thread.
// dynamic LDS: A tile padded to 129 (33024B) + W slice 128x64 (32768B) = 65792B
__global__ __launch_bounds__(256) void k_gemm(const float* __restrict__ A,
                                              const float* __restrict__ Wg,
                                              const float* __restrict__ bg,
                                              float* __restrict__ out, int M, int layer) {
    extern __shared__ float smem[];
    float* Al = smem;            // [64][129]
    float* Wl = smem + 64 * 129; // [128][64]
    const float* W = Wg + (size_t)layer * D * D;
    const float* b = bg + (size_t)layer * D;
    int row0 = blockIdx.x * 64;
    int col0 = blockIdx.y * 64;
    int t = threadIdx.x;
#pragma unroll
    for (int i = 0; i < 8; i++) {  // stage A: 64x128 = 2048 float4
        int f = t + i * 256;
        int r = f >> 5, k4 = f & 31;
        float4 v = make_float4(0.f, 0.f, 0.f, 0.f);
        int gr = row0 + r;
        if (gr < M) v = *(const float4*)(A + (size_t)gr * D + k4 * 4);
        float* dp = &Al[r * 129 + k4 * 4];
        dp[0] = v.x; dp[1] = v.y; dp[2] = v.z; dp[3] = v.w;
    }
#pragma unroll
    for (int i = 0; i < 8; i++) {  // stage W slice: 128x64 = 2048 float4
        int f = t + i * 256;
        int k = f >> 4, c4 = f & 15;
        *(float4*)&Wl[k * 64 + c4 * 4] = *(const float4*)(W + (size_t)k * D + col0 + c4 * 4);
    }
    __syncthreads();
    int tr = t & 15, tc = t >> 4;
    int r0 = tr * 4, c0 = tc * 4;
    float acc[4][4] = {};
#pragma unroll 4
    for (int k = 0; k < D; k++) {
        float a0 = Al[(r0 + 0) * 129 + k];
        float a1 = Al[(r0 + 1) * 129 + k];
        float a2 = Al[(r0 + 2) * 129 + k];
        float a3 = Al[(r0 + 3) * 129 + k];
        float4 w = *(float4*)&Wl[k * 64 + c0];
        acc[0][0] += a0 * w.x; acc[0][1] += a0 * w.y; acc[0][2] += a0 * w.z; acc[0][3] += a0 * w.w;
        acc[1][0] += a1 * w.x; acc[1][1] += a1 * w.y; acc[1][2] += a1 * w.z; acc[1][3] += a1 * w.w;
        acc[2][0] += a2 * w.x; acc[2][1] += a2 * w.y; acc[2][2] += a2 * w.z; acc[2][3] += a2 * w.w;
        acc[3][0] += a3 * w.x; acc[3][1] += a3 * w.y; acc[3][2] += a3 * w.z; acc[3][3] += a3 * w.w;
    }
    float4 bv = *(const float4*)(b + col0 + c0);
#pragma unroll
    for (int r = 0; r < 4; r++) {
        int gr = row0 + r0 + r;
        if (gr < M) {
            float4 o = make_float4(acc[r][0] + bv.x, acc[r][1] + bv.y,
                                   acc[r][2] + bv.z, acc[r][3] + bv.w);
            *(float4*)(out + (size_t)gr * D + col0 + c0) = o;
        }
    }
}

// ---------------- final: out = pacc * pinv ----------------
__global__ void k_final(const float* __restrict__ pacc, const float* __restrict__ pinv,
                        float* __restrict__ out, int n) {
    int i = blockIdx.x * 256 + threadIdx.x;
    if (i >= n) return;
    out[i] = pacc[i] * pinv[i >> 7];
}

extern "C" void kernel_launch(void* const* d_in, const int* in_sizes, int n_in,
                              void* d_out, int out_size, void* d_ws, size_t ws_size,
                              hipStream_t stream) {
    const float* x    = (const float*)d_in[0];
    const float* ea   = (const float*)d_in[1];
    const int* nm     = (const int*)d_in[2];
    const int* em     = (const int*)d_in[3];
    const int* cs     = (const int*)d_in[4];
    const int* batch  = (const int*)d_in[5];
    const float* Wg   = (const float*)d_in[7];
    const float* bg   = (const float*)d_in[8];
    const float* eps  = (const float*)d_in[9];
    const float* Wu   = (const float*)d_in[10];
    const float* bu   = (const float*)d_in[11];
    float* out = (float*)d_out;

    int N  = in_sizes[0] / D;
    int M  = in_sizes[2];
    int EC = in_sizes[3];
    int P  = out_size / D;
    const int* src = cs;
    const int* dst = cs + EC;

    float* ws = (float*)d_ws;
    size_t off = 0;
    float* h    = ws + off; off += (size_t)M * D;
    float* agg  = ws + off; off += (size_t)M * D;
    float* nacc = ws + off; off += (size_t)N * D;
    float* pacc = ws + off; off += (size_t)P * D;
    float* pmu  = ws + off; off += (size_t)P * D;
    float* ncnt = ws + off; off += N;
    float* pcnt = ws + off; off += P;
    if (ws_size < off * sizeof(float)) return;  // insufficient scratch: fail cleanly

    // per-segment inverse counts (static across layers)
    hipMemsetAsync(ncnt, 0, (size_t)(N + P) * sizeof(float), stream);
    k_count<<<(M + 255) / 256, 256, 0, stream>>>(nm, batch, ncnt, pcnt, M);
    k_invert<<<(N + P + 255) / 256, 256, 0, stream>>>(ncnt, N + P);

    int mb  = (M * 32 + 255) / 256;
    int ecb = (EC * 32 + 255) / 256;

    k_gather_init<<<mb, 256, 0, stream>>>((const f4*)x, nm, (f4*)h, (f4*)agg, eps, M);

    for (int i = 0; i < 4; i++) {
        if (i > 0) {
            hipMemsetAsync(pacc, 0, (size_t)P * D * sizeof(float), stream);
            k_patch_accum<<<mb, 256, 0, stream>>>((const f4*)h, batch, pacc, M);
            k_pmu<<<P, 128, 0, stream>>>(pacc, pcnt, Wu, bu, pmu, i - 1);
            hipMemsetAsync(nacc, 0, (size_t)N * D * sizeof(float), stream);
            k_update_node<<<mb, 256, 0, stream>>>((f4*)h, (const f4*)pmu, batch, nm, nacc, M);
            k_gather_mean_scale<<<mb, 256, 0, stream>>>((const f4*)nacc, ncnt, nm,
                                                        (f4*)h, (f4*)agg, eps, i, M);
        }
        k_edge<<<ecb, 256, 0, stream>>>((const f4*)h, (const f4*)ea, src, dst, em, agg, EC);
        dim3 gg((M + 63) / 64, 2);
        k_gemm<<<gg, 256, (64 * 129 + 128 * 64) * sizeof(float), stream>>>(agg, Wg, bg, h, M, i);
    }

    hipMemsetAsync(pacc, 0, (size_t)P * D * sizeof(float), stream);
    k_patch_accum<<<mb, 256, 0, stream>>>((const f4*)h, batch, pacc, M);
    k_final<<<(P * D + 255) / 256, 256, 0, stream>>>(pacc, pcnt, out, P * D);
}

// Round 2
// 1742.268 us; speedup vs baseline: 5.1565x; 5.1565x over previous
//
#include <hip/hip_runtime.h>

#define D 128
#define DV 32   // float4 per row

typedef float4 f4;

__device__ __forceinline__ void f4add(f4& a, const f4& b) {
    a.x += b.x; a.y += b.y; a.z += b.z; a.w += b.w;
}

// ================= build phase =================
__global__ void k_hist_edges(const int* __restrict__ dst, int* __restrict__ ecnt, int EC) {
    int c = blockIdx.x * 256 + threadIdx.x;
    if (c < EC) atomicAdd(&ecnt[dst[c]], 1);
}

__global__ void k_hist_nodes(const int* __restrict__ nm, const int* __restrict__ batch,
                             int* __restrict__ ncnt, int* __restrict__ pcnt, int M) {
    int m = blockIdx.x * 256 + threadIdx.x;
    if (m < M) { atomicAdd(&ncnt[nm[m]], 1); atomicAdd(&pcnt[batch[m]], 1); }
}

// exclusive scan, span 1024 per block
__global__ __launch_bounds__(256) void k_scan1(const int* __restrict__ in, int* __restrict__ out,
                                               int* __restrict__ bsum, int n) {
    __shared__ int ts[256];
    int b = blockIdx.x, t = threadIdx.x;
    int base = b * 1024 + t * 4;
    int v0 = base + 0 < n ? in[base + 0] : 0;
    int v1 = base + 1 < n ? in[base + 1] : 0;
    int v2 = base + 2 < n ? in[base + 2] : 0;
    int v3 = base + 3 < n ? in[base + 3] : 0;
    int tot = v0 + v1 + v2 + v3;
    ts[t] = tot; __syncthreads();
    for (int off = 1; off < 256; off <<= 1) {
        int x = (t >= off) ? ts[t - off] : 0; __syncthreads();
        ts[t] += x; __syncthreads();
    }
    int ex = ts[t] - tot;
    if (base + 0 < n) out[base + 0] = ex;
    if (base + 1 < n) out[base + 1] = ex + v0;
    if (base + 2 < n) out[base + 2] = ex + v0 + v1;
    if (base + 3 < n) out[base + 3] = ex + v0 + v1 + v2;
    if (t == 255) bsum[b] = ts[255];
}

__global__ void k_scan2(int* bsum, int nb) {
    if (threadIdx.x == 0) {
        int run = 0;
        for (int i = 0; i < nb; i++) { int x = bsum[i]; bsum[i] = run; run += x; }
    }
}

__global__ void k_scan3(int* __restrict__ out, const int* __restrict__ bsum, int n) {
    int i = blockIdx.x * 256 + threadIdx.x;
    if (i < n) out[i] += bsum[i >> 10];
}

__global__ void k_scatter_edges(const int* __restrict__ dst, int* __restrict__ ecur,
                                int* __restrict__ elist, int EC) {
    int c = blockIdx.x * 256 + threadIdx.x;
    if (c < EC) { int p = atomicAdd(&ecur[dst[c]], 1); elist[p] = c; }
}

__global__ void k_scatter_nodes(const int* __restrict__ nm, int* __restrict__ ncur,
                                int* __restrict__ mlist, int M) {
    int m = blockIdx.x * 256 + threadIdx.x;
    if (m < M) { int p = atomicAdd(&ncur[nm[m]], 1); mlist[p] = m; }
}

// ================= compute phase =================
__global__ void k_gather_init(const f4* __restrict__ x, const int* __restrict__ nm,
                              f4* __restrict__ h, int M) {
    int idx = blockIdx.x * 256 + threadIdx.x;
    int m = idx >> 5, j = idx & 31;
    if (m >= M) return;
    h[(size_t)m * DV + j] = x[(size_t)nm[m] * DV + j];
}

// agg[d] = (1+eps)*h[d] + sum_{edges into d} relu(h[src]+ea[em])   (no atomics)
__global__ __launch_bounds__(256) void k_edge_csr(const f4* __restrict__ h, const f4* __restrict__ ea,
                                                  const int* __restrict__ src, const int* __restrict__ em,
                                                  const int* __restrict__ elist, const int* __restrict__ estart,
                                                  const int* __restrict__ ecnt, f4* __restrict__ agg,
                                                  const float* __restrict__ eps, int layer, int M) {
    int idx = blockIdx.x * 256 + threadIdx.x;
    int d = idx >> 5, j = idx & 31;
    if (d >= M) return;
    f4 hd = h[(size_t)d * DV + j];
    float s = 1.0f + eps[layer];
    f4 acc = make_float4(hd.x * s, hd.y * s, hd.z * s, hd.w * s);
    int k0 = estart[d], kn = k0 + ecnt[d];
    for (int k = k0; k < kn; k++) {
        int c = elist[k];
        int sv = src[c], e = em[c];
        f4 hv = h[(size_t)sv * DV + j];
        f4 ev = ea[(size_t)e * DV + j];
        acc.x += fmaxf(hv.x + ev.x, 0.f);
        acc.y += fmaxf(hv.y + ev.y, 0.f);
        acc.z += fmaxf(hv.z + ev.z, 0.f);
        acc.w += fmaxf(hv.w + ev.w, 0.f);
    }
    agg[(size_t)d * DV + j] = acc;
}

// block per patch; batch is sorted so rows are contiguous [pstart, pstart+pcnt)
__global__ __launch_bounds__(256) void k_patch_mean(const f4* __restrict__ h, const int* __restrict__ pstart,
                                                    const int* __restrict__ pcnt, f4* __restrict__ outMean) {
    int p = blockIdx.x;
    int t = threadIdx.x, j = t & 31, r = t >> 5;  // 8 row-groups x 32 lanes
    int s0 = pstart[p], c = pcnt[p];
    f4 acc = make_float4(0.f, 0.f, 0.f, 0.f);
    for (int k = r; k < c; k += 8) f4add(acc, h[(size_t)(s0 + k) * DV + j]);
    __shared__ f4 red[256];
    red[t] = acc; __syncthreads();
    for (int step = 4; step >= 1; step >>= 1) {
        if (r < step) f4add(red[t], red[t + 32 * step]);
        __syncthreads();
    }
    if (r == 0) {
        f4 a = red[j];
        float inv = 1.0f / fmaxf((float)c, 1.0f);
        a.x *= inv; a.y *= inv; a.z *= inv; a.w *= inv;
        outMean[(size_t)p * DV + j] = a;
    }
}

// pmu = relu(pmean @ Wu[l] + bu[l])
__global__ __launch_bounds__(128) void k_pmu(const float* __restrict__ pmean, const float* __restrict__ Wu,
                                             const float* __restrict__ bu, float* __restrict__ pmu, int layer) {
    int p = blockIdx.x, cthr = threadIdx.x;
    const float* W = Wu + (size_t)layer * D * D;
    __shared__ float row[D];
    row[cthr] = pmean[(size_t)p * D + cthr];
    __syncthreads();
    float acc = bu[layer * D + cthr];
#pragma unroll 8
    for (int k = 0; k < D; k++) acc += row[k] * W[(size_t)k * D + cthr];
    pmu[(size_t)p * D + cthr] = fmaxf(acc, 0.f);
}

// per node n: mean over its copies of (h[m] + pmu[batch[m]]); write mean back to all copies
__global__ __launch_bounds__(256) void k_node_update(f4* __restrict__ h, const f4* __restrict__ pmu,
                                                     const int* __restrict__ batch, const int* __restrict__ mlist,
                                                     const int* __restrict__ nstart, const int* __restrict__ ncnt,
                                                     int N) {
    int idx = blockIdx.x * 256 + threadIdx.x;
    int n = idx >> 5, j = idx & 31;
    if (n >= N) return;
    int s0 = nstart[n], c = ncnt[n];
    f4 acc = make_float4(0.f, 0.f, 0.f, 0.f);
    for (int k = 0; k < c; k++) {
        int m = mlist[s0 + k];
        f4 hv = h[(size_t)m * DV + j];
        f4 u = pmu[(size_t)batch[m] * DV + j];
        acc.x += hv.x + u.x; acc.y += hv.y + u.y;
        acc.z += hv.z + u.z; acc.w += hv.w + u.w;
    }
    float inv = 1.0f / fmaxf((float)c, 1.0f);
    acc.x *= inv; acc.y *= inv; acc.z *= inv; acc.w *= inv;
    for (int k = 0; k < c; k++) {
        int m = mlist[s0 + k];
        h[(size_t)m * DV + j] = acc;
    }
}

// ---------------- GEMM: out[M,128] = A[M,128] @ W[l] + b[l] ----------------
__global__ __launch_bounds__(256) void k_gemm(const float* __restrict__ A,
                                              const float* __restrict__ Wg,
                                              const float* __restrict__ bg,
                                              float* __restrict__ out, int M, int layer) {
    extern __shared__ float smem[];
    float* Al = smem;            // [64][129]
    float* Wl = smem + 64 * 129; // [128][64]
    const float* W = Wg + (size_t)layer * D * D;
    const float* b = bg + (size_t)layer * D;
    int row0 = blockIdx.x * 64;
    int col0 = blockIdx.y * 64;
    int t = threadIdx.x;
#pragma unroll
    for (int i = 0; i < 8; i++) {
        int f = t + i * 256;
        int r = f >> 5, k4 = f & 31;
        float4 v = make_float4(0.f, 0.f, 0.f, 0.f);
        int gr = row0 + r;
        if (gr < M) v = *(const float4*)(A + (size_t)gr * D + k4 * 4);
        float* dp = &Al[r * 129 + k4 * 4];
        dp[0] = v.x; dp[1] = v.y; dp[2] = v.z; dp[3] = v.w;
    }
#pragma unroll
    for (int i = 0; i < 8; i++) {
        int f = t + i * 256;
        int k = f >> 4, c4 = f & 15;
        *(float4*)&Wl[k * 64 + c4 * 4] = *(const float4*)(W + (size_t)k * D + col0 + c4 * 4);
    }
    __syncthreads();
    int tr = t & 15, tc = t >> 4;
    int r0 = tr * 4, c0 = tc * 4;
    float acc[4][4] = {};
#pragma unroll 4
    for (int k = 0; k < D; k++) {
        float a0 = Al[(r0 + 0) * 129 + k];
        float a1 = Al[(r0 + 1) * 129 + k];
        float a2 = Al[(r0 + 2) * 129 + k];
        float a3 = Al[(r0 + 3) * 129 + k];
        float4 w = *(float4*)&Wl[k * 64 + c0];
        acc[0][0] += a0 * w.x; acc[0][1] += a0 * w.y; acc[0][2] += a0 * w.z; acc[0][3] += a0 * w.w;
        acc[1][0] += a1 * w.x; acc[1][1] += a1 * w.y; acc[1][2] += a1 * w.z; acc[1][3] += a1 * w.w;
        acc[2][0] += a2 * w.x; acc[2][1] += a2 * w.y; acc[2][2] += a2 * w.z; acc[2][3] += a2 * w.w;
        acc[3][0] += a3 * w.x; acc[3][1] += a3 * w.y; acc[3][2] += a3 * w.z; acc[3][3] += a3 * w.w;
    }
    float4 bv = *(const float4*)(b + col0 + c0);
#pragma unroll
    for (int r = 0; r < 4; r++) {
        int gr = row0 + r0 + r;
        if (gr < M) {
            float4 o = make_float4(acc[r][0] + bv.x, acc[r][1] + bv.y,
                                   acc[r][2] + bv.z, acc[r][3] + bv.w);
            *(float4*)(out + (size_t)gr * D + col0 + c0) = o;
        }
    }
}

extern "C" void kernel_launch(void* const* d_in, const int* in_sizes, int n_in,
                              void* d_out, int out_size, void* d_ws, size_t ws_size,
                              hipStream_t stream) {
    const float* x    = (const float*)d_in[0];
    const float* ea   = (const float*)d_in[1];
    const int* nm     = (const int*)d_in[2];
    const int* em     = (const int*)d_in[3];
    const int* cs     = (const int*)d_in[4];
    const int* batch  = (const int*)d_in[5];
    const float* Wg   = (const float*)d_in[7];
    const float* bg   = (const float*)d_in[8];
    const float* eps  = (const float*)d_in[9];
    const float* Wu   = (const float*)d_in[10];
    const float* bu   = (const float*)d_in[11];
    float* out = (float*)d_out;

    int N  = in_sizes[0] / D;
    int M  = in_sizes[2];
    int EC = in_sizes[3];
    int P  = out_size / D;
    const int* src = cs;
    const int* dst = cs + EC;

    // workspace carve
    char* base = (char*)d_ws;
    size_t off = 0;
    auto carveF = [&](size_t n) { float* p = (float*)(base + off); off += n * sizeof(float); return p; };
    auto carveI = [&](size_t n) { int* p = (int*)(base + off); off += n * sizeof(int); return p; };
    float* h     = carveF((size_t)M * D);
    float* agg   = carveF((size_t)M * D);
    float* pmean = carveF((size_t)P * D);
    float* pmu   = carveF((size_t)P * D);
    int* ecnt   = carveI(M);   // contiguous cnt block: ecnt, ncnt, pcnt
    int* ncnt   = carveI(N);
    int* pcnt   = carveI(P);
    int* estart = carveI(M);
    int* ecur   = carveI(M);
    int* elist  = carveI(EC);
    int* nstart = carveI(N);
    int* ncur   = carveI(N);
    int* mlist  = carveI(M);
    int* pstart = carveI(P);
    int* bsum   = carveI(1024);
    if (ws_size < off) return;

    // ---- build CSR structures (once; reused for all 4 layers) ----
    hipMemsetAsync(ecnt, 0, (size_t)(M + N + P) * sizeof(int), stream);
    k_hist_edges<<<(EC + 255) / 256, 256, 0, stream>>>(dst, ecnt, EC);
    k_hist_nodes<<<(M + 255) / 256, 256, 0, stream>>>(nm, batch, ncnt, pcnt, M);

    auto scan = [&](const int* in, int* outp, int n) {
        int nb = (n + 1023) / 1024;
        k_scan1<<<nb, 256, 0, stream>>>(in, outp, bsum, n);
        k_scan2<<<1, 64, 0, stream>>>(bsum, nb);
        k_scan3<<<(n + 255) / 256, 256, 0, stream>>>(outp, bsum, n);
    };
    scan(ecnt, estart, M);
    scan(ncnt, nstart, N);
    scan(pcnt, pstart, P);

    hipMemcpyAsync(ecur, estart, (size_t)M * sizeof(int), hipMemcpyDeviceToDevice, stream);
    hipMemcpyAsync(ncur, nstart, (size_t)N * sizeof(int), hipMemcpyDeviceToDevice, stream);
    k_scatter_edges<<<(EC + 255) / 256, 256, 0, stream>>>(dst, ecur, elist, EC);
    k_scatter_nodes<<<(M + 255) / 256, 256, 0, stream>>>(nm, ncur, mlist, M);

    // ---- compute ----
    int mb = (M * 32 + 255) / 256;
    k_gather_init<<<mb, 256, 0, stream>>>((const f4*)x, nm, (f4*)h, M);

    for (int i = 0; i < 4; i++) {
        if (i > 0) {
            k_patch_mean<<<P, 256, 0, stream>>>((const f4*)h, pstart, pcnt, (f4*)pmean);
            k_pmu<<<P, 128, 0, stream>>>(pmean, Wu, bu, pmu, i - 1);
            k_node_update<<<(N * 32 + 255) / 256, 256, 0, stream>>>((f4*)h, (const f4*)pmu,
                                                                    batch, mlist, nstart, ncnt, N);
        }
        k_edge_csr<<<mb, 256, 0, stream>>>((const f4*)h, (const f4*)ea, src, em,
                                           elist, estart, ecnt, (f4*)agg, eps, i, M);
        dim3 gg((M + 63) / 64, 2);
        k_gemm<<<gg, 256, (64 * 129 + 128 * 64) * sizeof(float), stream>>>(agg, Wg, bg, h, M, i);
    }

    k_patch_mean<<<P, 256, 0, stream>>>((const f4*)h, pstart, pcnt, (f4*)out);
}

// Round 3
// 1033.187 us; speedup vs baseline: 8.6955x; 1.6863x over previous
//
#include <hip/hip_runtime.h>
#include <hip/hip_bf16.h>

#define D 128
#define DV 32   // float4 per row

typedef float4 f4;
typedef unsigned short ushort_t;
typedef __attribute__((ext_vector_type(8))) short short8;
typedef __attribute__((ext_vector_type(4))) float f32x4;

__device__ __forceinline__ void f4add(f4& a, const f4& b) {
    a.x += b.x; a.y += b.y; a.z += b.z; a.w += b.w;
}
__device__ __forceinline__ float b2f(ushort_t u) {
    union { unsigned int i; float f; } v; v.i = ((unsigned int)u) << 16; return v.f;
}
__device__ __forceinline__ ushort_t f2b(float f) {
    __hip_bfloat16 b = __float2bfloat16(f);
    return *reinterpret_cast<ushort_t*>(&b);
}

// ================= build phase =================
__global__ void k_hist_edges(const int* __restrict__ dst, int* __restrict__ ecnt, int EC) {
    int c = blockIdx.x * 256 + threadIdx.x;
    if (c < EC) atomicAdd(&ecnt[dst[c]], 1);
}

__global__ void k_hist_nodes(const int* __restrict__ nm, const int* __restrict__ batch,
                             int* __restrict__ ncnt, int* __restrict__ pcnt, int M) {
    int m = blockIdx.x * 256 + threadIdx.x;
    if (m < M) { atomicAdd(&ncnt[nm[m]], 1); atomicAdd(&pcnt[batch[m]], 1); }
}

// exclusive scan, span 1024 per block
__global__ __launch_bounds__(256) void k_scan1(const int* __restrict__ in, int* __restrict__ out,
                                               int* __restrict__ bsum, int n) {
    __shared__ int ts[256];
    int b = blockIdx.x, t = threadIdx.x;
    int base = b * 1024 + t * 4;
    int v0 = base + 0 < n ? in[base + 0] : 0;
    int v1 = base + 1 < n ? in[base + 1] : 0;
    int v2 = base + 2 < n ? in[base + 2] : 0;
    int v3 = base + 3 < n ? in[base + 3] : 0;
    int tot = v0 + v1 + v2 + v3;
    ts[t] = tot; __syncthreads();
    for (int off = 1; off < 256; off <<= 1) {
        int x = (t >= off) ? ts[t - off] : 0; __syncthreads();
        ts[t] += x; __syncthreads();
    }
    int ex = ts[t] - tot;
    if (base + 0 < n) out[base + 0] = ex;
    if (base + 1 < n) out[base + 1] = ex + v0;
    if (base + 2 < n) out[base + 2] = ex + v0 + v1;
    if (base + 3 < n) out[base + 3] = ex + v0 + v1 + v2;
    if (t == 255) bsum[b] = ts[255];
}

__global__ void k_scan2(int* bsum, int nb) {
    if (threadIdx.x == 0) {
        int run = 0;
        for (int i = 0; i < nb; i++) { int x = bsum[i]; bsum[i] = run; run += x; }
    }
}

__global__ void k_scan3(int* __restrict__ out, const int* __restrict__ bsum, int n) {
    int i = blockIdx.x * 256 + threadIdx.x;
    if (i < n) out[i] += bsum[i >> 10];
}

// scatter: nsrc[p] = node-of-src, eem[p] = edge attr index (cursor becomes END pointer)
__global__ void k_scatter_edges(const int* __restrict__ dst, const int* __restrict__ src,
                                const int* __restrict__ em, const int* __restrict__ nm,
                                int* __restrict__ ecur, int* __restrict__ nsrc,
                                int* __restrict__ eem, int EC) {
    int c = blockIdx.x * 256 + threadIdx.x;
    if (c >= EC) return;
    int p = atomicAdd(&ecur[dst[c]], 1);
    nsrc[p] = nm[src[c]];
    eem[p] = em[c];
}

__global__ void k_scatter_nodes(const int* __restrict__ nm, int* __restrict__ ncur,
                                int* __restrict__ mlist, int M) {
    int m = blockIdx.x * 256 + threadIdx.x;
    if (m < M) { int p = atomicAdd(&ncur[nm[m]], 1); mlist[p] = m; }
}

// ea f32 -> bf16 (8 elems per thread)
__global__ void k_ea2bf(const float* __restrict__ ea, ushort_t* __restrict__ eab, int n8) {
    int i = blockIdx.x * 256 + threadIdx.x;
    if (i >= n8) return;
    const f4* p = (const f4*)ea + (size_t)i * 2;
    f4 v0 = p[0], v1 = p[1];
    ushort4 o0, o1;
    o0.x = f2b(v0.x); o0.y = f2b(v0.y); o0.z = f2b(v0.z); o0.w = f2b(v0.w);
    o1.x = f2b(v1.x); o1.y = f2b(v1.y); o1.z = f2b(v1.z); o1.w = f2b(v1.w);
    *(ushort4*)(eab + (size_t)i * 8) = o0;
    *(ushort4*)(eab + (size_t)i * 8 + 4) = o1;
}

// W[l][k][col] f32 -> Wtb[l][col][k] bf16 (transposed)
__global__ void k_prepW(const float* __restrict__ Wg, ushort_t* __restrict__ Wtb, int total) {
    int i = blockIdx.x * 256 + threadIdx.x;
    if (i >= total) return;
    int l = i >> 14, rem = i & 16383;
    int col = rem >> 7, k = rem & 127;
    Wtb[(size_t)l * 16384 + col * 128 + k] = f2b(Wg[(size_t)l * 16384 + k * 128 + col]);
}

// ================= compute phase =================
// aggb[d] = bf16( (1+eps)*hn[nm[d]] + sum relu(hn[nsrc]+eab[eem]) )
__global__ __launch_bounds__(256) void k_edge(const f4* __restrict__ hn, const ushort_t* __restrict__ eab,
                                              const int* __restrict__ nm, const int* __restrict__ nsrc,
                                              const int* __restrict__ eem, const int* __restrict__ eend,
                                              const int* __restrict__ ecnt, ushort_t* __restrict__ aggb,
                                              const float* __restrict__ eps, int layer, int M) {
    int idx = blockIdx.x * 256 + threadIdx.x;
    int d = idx >> 5, j = idx & 31;
    if (d >= M) return;
    f4 hd = hn[(size_t)nm[d] * DV + j];
    float s = 1.0f + eps[layer];
    f4 acc = make_float4(hd.x * s, hd.y * s, hd.z * s, hd.w * s);
    int kn = eend[d], k0 = kn - ecnt[d];
    for (int k = k0; k < kn; k++) {
        int sv = nsrc[k], ev = eem[k];
        f4 hv = hn[(size_t)sv * DV + j];
        ushort4 eb = *(const ushort4*)(eab + (size_t)ev * D + j * 4);
        acc.x += fmaxf(hv.x + b2f(eb.x), 0.f);
        acc.y += fmaxf(hv.y + b2f(eb.y), 0.f);
        acc.z += fmaxf(hv.z + b2f(eb.z), 0.f);
        acc.w += fmaxf(hv.w + b2f(eb.w), 0.f);
    }
    ushort4 o;
    o.x = f2b(acc.x); o.y = f2b(acc.y); o.z = f2b(acc.z); o.w = f2b(acc.w);
    *(ushort4*)(aggb + (size_t)d * D + j * 4) = o;
}

// h[M,128] = aggb[M,128](bf16) @ W[l] + b[l], MFMA 16x16x32, 64 rows/block, full 128 cols
__global__ __launch_bounds__(256) void k_gemm(const ushort_t* __restrict__ aggb,
                                              const ushort_t* __restrict__ Wtb,
                                              const float* __restrict__ bg,
                                              float* __restrict__ h, int M, int layer) {
    __shared__ ushort_t Wl[128 * 136];  // [col][k] padded
    const ushort_t* W = Wtb + (size_t)layer * D * D;
    int t = threadIdx.x;
#pragma unroll
    for (int i = 0; i < 8; i++) {
        int cid = t + i * 256;              // 2048 chunks of 8 bf16
        int col = cid >> 4, kc = (cid & 15) * 8;
        *(short8*)&Wl[col * 136 + kc] = *(const short8*)(W + col * 128 + kc);
    }
    __syncthreads();
    int w = t >> 6, lane = t & 63;
    int r16 = lane & 15, kg = lane >> 4;
    int rowbase = blockIdx.x * 64 + w * 16;
    size_t arow = (size_t)min(rowbase + r16, M - 1) * D;
    short8 a0 = *(const short8*)(aggb + arow + 0 + kg * 8);
    short8 a1 = *(const short8*)(aggb + arow + 32 + kg * 8);
    short8 a2 = *(const short8*)(aggb + arow + 64 + kg * 8);
    short8 a3 = *(const short8*)(aggb + arow + 96 + kg * 8);
    f32x4 acc[8];
#pragma unroll
    for (int c = 0; c < 8; c++) acc[c] = (f32x4){0.f, 0.f, 0.f, 0.f};
#pragma unroll
    for (int c = 0; c < 8; c++) {
        const ushort_t* wp = &Wl[(c * 16 + r16) * 136 + kg * 8];
        short8 b0 = *(const short8*)(wp + 0);
        short8 b1 = *(const short8*)(wp + 32);
        short8 b2 = *(const short8*)(wp + 64);
        short8 b3 = *(const short8*)(wp + 96);
        acc[c] = __builtin_amdgcn_mfma_f32_16x16x32_bf16(a0, b0, acc[c], 0, 0, 0);
        acc[c] = __builtin_amdgcn_mfma_f32_16x16x32_bf16(a1, b1, acc[c], 0, 0, 0);
        acc[c] = __builtin_amdgcn_mfma_f32_16x16x32_bf16(a2, b2, acc[c], 0, 0, 0);
        acc[c] = __builtin_amdgcn_mfma_f32_16x16x32_bf16(a3, b3, acc[c], 0, 0, 0);
    }
#pragma unroll
    for (int c = 0; c < 8; c++) {
        int gcol = c * 16 + r16;
        float bias = bg[layer * D + gcol];
#pragma unroll
        for (int q = 0; q < 4; q++) {
            int grow = rowbase + kg * 4 + q;
            if (grow < M) h[(size_t)grow * D + gcol] = acc[c][q] + bias;
        }
    }
}

// block per patch; batch sorted -> contiguous [pstart, pstart+pcnt)
__global__ __launch_bounds__(256) void k_patch_mean(const f4* __restrict__ h, const int* __restrict__ pstart,
                                                    const int* __restrict__ pcnt, f4* __restrict__ outMean) {
    int p = blockIdx.x;
    int t = threadIdx.x, j = t & 31, r = t >> 5;
    int s0 = pstart[p], c = pcnt[p];
    f4 acc = make_float4(0.f, 0.f, 0.f, 0.f);
    for (int k = r; k < c; k += 8) f4add(acc, h[(size_t)(s0 + k) * DV + j]);
    __shared__ f4 red[256];
    red[t] = acc; __syncthreads();
    for (int step = 4; step >= 1; step >>= 1) {
        if (r < step) f4add(red[t], red[t + 32 * step]);
        __syncthreads();
    }
    if (r == 0) {
        f4 a = red[j];
        float inv = 1.0f / fmaxf((float)c, 1.0f);
        a.x *= inv; a.y *= inv; a.z *= inv; a.w *= inv;
        outMean[(size_t)p * DV + j] = a;
    }
}

// pmu = relu(pmean @ Wu[l] + bu[l])
__global__ __launch_bounds__(128) void k_pmu(const float* __restrict__ pmean, const float* __restrict__ Wu,
                                             const float* __restrict__ bu, float* __restrict__ pmu, int layer) {
    int p = blockIdx.x, cthr = threadIdx.x;
    const float* W = Wu + (size_t)layer * D * D;
    __shared__ float row[D];
    row[cthr] = pmean[(size_t)p * D + cthr];
    __syncthreads();
    float acc = bu[layer * D + cthr];
#pragma unroll 8
    for (int k = 0; k < D; k++) acc += row[k] * W[(size_t)k * D + cthr];
    pmu[(size_t)p * D + cthr] = fmaxf(acc, 0.f);
}

// hn[n] = mean over copies of (h[m] + pmu[batch[m]])
__global__ __launch_bounds__(256) void k_node_update(const f4* __restrict__ h, const f4* __restrict__ pmu,
                                                     const int* __restrict__ batch, const int* __restrict__ mlist,
                                                     const int* __restrict__ nend, const int* __restrict__ ncnt,
                                                     f4* __restrict__ hn, int N) {
    int idx = blockIdx.x * 256 + threadIdx.x;
    int n = idx >> 5, j = idx & 31;
    if (n >= N) return;
    int kn = nend[n], c = ncnt[n], s0 = kn - c;
    f4 acc = make_float4(0.f, 0.f, 0.f, 0.f);
    for (int k = 0; k < c; k++) {
        int m = mlist[s0 + k];
        f4 hv = h[(size_t)m * DV + j];
        f4 u = pmu[(size_t)batch[m] * DV + j];
        acc.x += hv.x + u.x; acc.y += hv.y + u.y;
        acc.z += hv.z + u.z; acc.w += hv.w + u.w;
    }
    float inv = 1.0f / fmaxf((float)c, 1.0f);
    acc.x *= inv; acc.y *= inv; acc.z *= inv; acc.w *= inv;
    hn[(size_t)n * DV + j] = acc;
}

extern "C" void kernel_launch(void* const* d_in, const int* in_sizes, int n_in,
                              void* d_out, int out_size, void* d_ws, size_t ws_size,
                              hipStream_t stream) {
    const float* x    = (const float*)d_in[0];
    const float* ea   = (const float*)d_in[1];
    const int* nm     = (const int*)d_in[2];
    const int* em     = (const int*)d_in[3];
    const int* cs     = (const int*)d_in[4];
    const int* batch  = (const int*)d_in[5];
    const float* Wg   = (const float*)d_in[7];
    const float* bg   = (const float*)d_in[8];
    const float* eps  = (const float*)d_in[9];
    const float* Wu   = (const float*)d_in[10];
    const float* bu   = (const float*)d_in[11];
    float* out = (float*)d_out;

    int N  = in_sizes[0] / D;
    int E  = in_sizes[1] / D;
    int M  = in_sizes[2];
    int EC = in_sizes[3];
    int P  = out_size / D;
    const int* src = cs;
    const int* dst = cs + EC;

    // workspace carve (256B aligned chunks)
    char* base = (char*)d_ws;
    size_t off = 0;
    auto carve = [&](size_t bytes) { void* p = base + off; off += (bytes + 255) & ~(size_t)255; return p; };
    float*    h     = (float*)carve((size_t)M * D * 4);
    float*    hn    = (float*)carve((size_t)N * D * 4);
    ushort_t* aggb  = (ushort_t*)carve((size_t)M * D * 2);
    ushort_t* eab   = (ushort_t*)carve((size_t)E * D * 2);
    ushort_t* Wtb   = (ushort_t*)carve((size_t)4 * D * D * 2);
    float*    pmean = (float*)carve((size_t)P * D * 4);
    float*    pmu   = (float*)carve((size_t)P * D * 4);
    int* cntblk = (int*)carve((size_t)(M + N + P) * 4);
    int* ecnt = cntblk, *ncnt = cntblk + M, *pcnt = cntblk + M + N;
    int* ecur   = (int*)carve((size_t)M * 4);
    int* ncur   = (int*)carve((size_t)N * 4);
    int* nsrc   = (int*)carve((size_t)EC * 4);
    int* eem    = (int*)carve((size_t)EC * 4);
    int* mlist  = (int*)carve((size_t)M * 4);
    int* pstart = (int*)carve((size_t)P * 4);
    int* bsum   = (int*)carve(1024 * 4);
    if (ws_size < off) return;

    // ---- build (reused across layers) ----
    hipMemsetAsync(cntblk, 0, (size_t)(M + N + P) * sizeof(int), stream);
    k_hist_edges<<<(EC + 255) / 256, 256, 0, stream>>>(dst, ecnt, EC);
    k_hist_nodes<<<(M + 255) / 256, 256, 0, stream>>>(nm, batch, ncnt, pcnt, M);

    auto scan = [&](const int* in, int* outp, int n) {
        int nb = (n + 1023) / 1024;
        k_scan1<<<nb, 256, 0, stream>>>(in, outp, bsum, n);
        k_scan2<<<1, 64, 0, stream>>>(bsum, nb);
        k_scan3<<<(n + 255) / 256, 256, 0, stream>>>(outp, bsum, n);
    };
    scan(ecnt, ecur, M);
    scan(ncnt, ncur, N);
    scan(pcnt, pstart, P);

    k_scatter_edges<<<(EC + 255) / 256, 256, 0, stream>>>(dst, src, em, nm, ecur, nsrc, eem, EC);
    k_scatter_nodes<<<(M + 255) / 256, 256, 0, stream>>>(nm, ncur, mlist, M);
    k_ea2bf<<<((E * D / 8) + 255) / 256, 256, 0, stream>>>(ea, eab, E * D / 8);
    k_prepW<<<(4 * D * D + 255) / 256, 256, 0, stream>>>(Wg, Wtb, 4 * D * D);

    // ---- compute: hn starts as x (node-uniform) ----
    int mb = (M * 32 + 255) / 256;
    for (int i = 0; i < 4; i++) {
        const f4* hnp = (i == 0) ? (const f4*)x : (const f4*)hn;
        if (i > 0) {
            k_patch_mean<<<P, 256, 0, stream>>>((const f4*)h, pstart, pcnt, (f4*)pmean);
            k_pmu<<<P, 128, 0, stream>>>(pmean, Wu, bu, pmu, i - 1);
            k_node_update<<<(N * 32 + 255) / 256, 256, 0, stream>>>((const f4*)h, (const f4*)pmu,
                                                                    batch, mlist, ncur, ncnt, (f4*)hn, N);
        }
        k_edge<<<mb, 256, 0, stream>>>(hnp, eab, nm, nsrc, eem, ecur, ecnt, aggb, eps, i, M);
        k_gemm<<<(M + 63) / 64, 256, 0, stream>>>(aggb, Wtb, bg, h, M, i);
    }

    k_patch_mean<<<P, 256, 0, stream>>>((const f4*)h, pstart, pcnt, (f4*)out);
}

// Round 4
// 911.237 us; speedup vs baseline: 9.8592x; 1.1338x over previous
//
#include <hip/hip_runtime.h>
#include <hip/hip_bf16.h>

#define D 128
#define DV 32   // float4 per row

typedef float4 f4;
typedef unsigned short ushort_t;
typedef __attribute__((ext_vector_type(8))) short short8;
typedef __attribute__((ext_vector_type(4))) float f32x4;

__device__ __forceinline__ void f4add(f4& a, const f4& b) {
    a.x += b.x; a.y += b.y; a.z += b.z; a.w += b.w;
}
__device__ __forceinline__ float b2f(ushort_t u) {
    union { unsigned int i; float f; } v; v.i = ((unsigned int)u) << 16; return v.f;
}
__device__ __forceinline__ ushort_t f2b(float f) {
    __hip_bfloat16 b = __float2bfloat16(f);
    return *reinterpret_cast<ushort_t*>(&b);
}

// ================= build phase =================
__global__ void k_hist_edges(const int* __restrict__ dst, int* __restrict__ ecnt, int EC) {
    int c = blockIdx.x * 256 + threadIdx.x;
    if (c < EC) atomicAdd(&ecnt[dst[c]], 1);
}

__global__ void k_hist_nodes(const int* __restrict__ nm, const int* __restrict__ batch,
                             int* __restrict__ ncnt, int* __restrict__ pcnt, int M) {
    int m = blockIdx.x * 256 + threadIdx.x;
    if (m < M) { atomicAdd(&ncnt[nm[m]], 1); atomicAdd(&pcnt[batch[m]], 1); }
}

// exclusive scan, span 1024 per block
__global__ __launch_bounds__(256) void k_scan1(const int* __restrict__ in, int* __restrict__ out,
                                               int* __restrict__ bsum, int n) {
    __shared__ int ts[256];
    int b = blockIdx.x, t = threadIdx.x;
    int base = b * 1024 + t * 4;
    int v0 = base + 0 < n ? in[base + 0] : 0;
    int v1 = base + 1 < n ? in[base + 1] : 0;
    int v2 = base + 2 < n ? in[base + 2] : 0;
    int v3 = base + 3 < n ? in[base + 3] : 0;
    int tot = v0 + v1 + v2 + v3;
    ts[t] = tot; __syncthreads();
    for (int off = 1; off < 256; off <<= 1) {
        int x = (t >= off) ? ts[t - off] : 0; __syncthreads();
        ts[t] += x; __syncthreads();
    }
    int ex = ts[t] - tot;
    if (base + 0 < n) out[base + 0] = ex;
    if (base + 1 < n) out[base + 1] = ex + v0;
    if (base + 2 < n) out[base + 2] = ex + v0 + v1;
    if (base + 3 < n) out[base + 3] = ex + v0 + v1 + v2;
    if (t == 255) bsum[b] = ts[255];
}

__global__ void k_scan2(int* bsum, int nb) {
    if (threadIdx.x == 0) {
        int run = 0;
        for (int i = 0; i < nb; i++) { int x = bsum[i]; bsum[i] = run; run += x; }
    }
}

__global__ void k_scan3(int* __restrict__ out, const int* __restrict__ bsum, int n) {
    int i = blockIdx.x * 256 + threadIdx.x;
    if (i < n) out[i] += bsum[i >> 10];
}

// scatter: nsrc[p] = node-of-src, eem[p] = edge attr index (cursor becomes END pointer)
__global__ void k_scatter_edges(const int* __restrict__ dst, const int* __restrict__ src,
                                const int* __restrict__ em, const int* __restrict__ nm,
                                int* __restrict__ ecur, int* __restrict__ nsrc,
                                int* __restrict__ eem, int EC) {
    int c = blockIdx.x * 256 + threadIdx.x;
    if (c >= EC) return;
    int p = atomicAdd(&ecur[dst[c]], 1);
    nsrc[p] = nm[src[c]];
    eem[p] = em[c];
}

__global__ void k_scatter_nodes(const int* __restrict__ nm, int* __restrict__ ncur,
                                int* __restrict__ mlist, int M) {
    int m = blockIdx.x * 256 + threadIdx.x;
    if (m < M) { int p = atomicAdd(&ncur[nm[m]], 1); mlist[p] = m; }
}

// ea f32 -> bf16 (8 elems per thread)
__global__ void k_ea2bf(const float* __restrict__ ea, ushort_t* __restrict__ eab, int n8) {
    int i = blockIdx.x * 256 + threadIdx.x;
    if (i >= n8) return;
    const f4* p = (const f4*)ea + (size_t)i * 2;
    f4 v0 = p[0], v1 = p[1];
    ushort4 o0, o1;
    o0.x = f2b(v0.x); o0.y = f2b(v0.y); o0.z = f2b(v0.z); o0.w = f2b(v0.w);
    o1.x = f2b(v1.x); o1.y = f2b(v1.y); o1.z = f2b(v1.z); o1.w = f2b(v1.w);
    *(ushort4*)(eab + (size_t)i * 8) = o0;
    *(ushort4*)(eab + (size_t)i * 8 + 4) = o1;
}

// W[l][k][col] f32 -> Wtb[l][col][k] bf16 (transposed)
__global__ void k_prepW(const float* __restrict__ Wg, ushort_t* __restrict__ Wtb, int total) {
    int i = blockIdx.x * 256 + threadIdx.x;
    if (i >= total) return;
    int l = i >> 14, rem = i & 16383;
    int col = rem >> 7, k = rem & 127;
    Wtb[(size_t)l * 16384 + col * 128 + k] = f2b(Wg[(size_t)l * 16384 + k * 128 + col]);
}

// ================= compute phase =================
// aggb[d] = bf16( (1+eps)*hn[nm[d]] + sum relu(hn[nsrc]+eab[eem]) )
__global__ __launch_bounds__(256) void k_edge(const f4* __restrict__ hn, const ushort_t* __restrict__ eab,
                                              const int* __restrict__ nm, const int* __restrict__ nsrc,
                                              const int* __restrict__ eem, const int* __restrict__ eend,
                                              const int* __restrict__ ecnt, ushort_t* __restrict__ aggb,
                                              const float* __restrict__ eps, int layer, int M) {
    int idx = blockIdx.x * 256 + threadIdx.x;
    int d = idx >> 5, j = idx & 31;
    if (d >= M) return;
    f4 hd = hn[(size_t)nm[d] * DV + j];
    float s = 1.0f + eps[layer];
    f4 acc = make_float4(hd.x * s, hd.y * s, hd.z * s, hd.w * s);
    int kn = eend[d], k0 = kn - ecnt[d];
    for (int k = k0; k < kn; k++) {
        int sv = nsrc[k], ev = eem[k];
        f4 hv = hn[(size_t)sv * DV + j];
        ushort4 eb = *(const ushort4*)(eab + (size_t)ev * D + j * 4);
        acc.x += fmaxf(hv.x + b2f(eb.x), 0.f);
        acc.y += fmaxf(hv.y + b2f(eb.y), 0.f);
        acc.z += fmaxf(hv.z + b2f(eb.z), 0.f);
        acc.w += fmaxf(hv.w + b2f(eb.w), 0.f);
    }
    ushort4 o;
    o.x = f2b(acc.x); o.y = f2b(acc.y); o.z = f2b(acc.z); o.w = f2b(acc.w);
    *(ushort4*)(aggb + (size_t)d * D + j * 4) = o;
}

// block per patch: aggP[p] = mean_{m in patch} aggb[m]  (contiguous rows, f32 accum)
__global__ __launch_bounds__(256) void k_patch_agg(const ushort_t* __restrict__ aggb,
                                                   const int* __restrict__ pstart,
                                                   const int* __restrict__ pcnt,
                                                   float* __restrict__ aggP) {
    int p = blockIdx.x;
    int t = threadIdx.x, j = t & 31, r = t >> 5;
    int s0 = pstart[p], c = pcnt[p];
    f4 acc = make_float4(0.f, 0.f, 0.f, 0.f);
    for (int k = r; k < c; k += 8) {
        ushort4 ab = *(const ushort4*)(aggb + (size_t)(s0 + k) * D + j * 4);
        acc.x += b2f(ab.x); acc.y += b2f(ab.y); acc.z += b2f(ab.z); acc.w += b2f(ab.w);
    }
    __shared__ f4 red[256];
    red[t] = acc; __syncthreads();
    for (int step = 4; step >= 1; step >>= 1) {
        if (r < step) f4add(red[t], red[t + 32 * step]);
        __syncthreads();
    }
    if (r == 0) {
        f4 a = red[j];
        float inv = 1.0f / fmaxf((float)c, 1.0f);
        a.x *= inv; a.y *= inv; a.z *= inv; a.w *= inv;
        *((f4*)(aggP + (size_t)p * D) + j) = a;
    }
}

// fused tiny transform per patch row:
//   pm = aggP[p] @ Wg[lw] + bg[lw]
//   doSecond ? outv[p] = relu(pm @ Wu[lu] + bu[lu]) : outv[p] = pm
__global__ __launch_bounds__(128) void k_ptf(const float* __restrict__ aggP,
                                             const float* __restrict__ Wg, const float* __restrict__ bg,
                                             const float* __restrict__ Wu, const float* __restrict__ bu,
                                             float* __restrict__ outv, int lw, int lu, int doSecond) {
    int p = blockIdx.x, c = threadIdx.x;
    __shared__ float row[D];
    __shared__ float mid[D];
    row[c] = aggP[(size_t)p * D + c];
    __syncthreads();
    const float* W = Wg + (size_t)lw * D * D;
    float acc = bg[lw * D + c];
#pragma unroll 8
    for (int k = 0; k < D; k++) acc += row[k] * W[k * D + c];
    if (!doSecond) { outv[(size_t)p * D + c] = acc; return; }
    mid[c] = acc;
    __syncthreads();
    const float* W2 = Wu + (size_t)lu * D * D;
    float a2 = bu[lu * D + c];
#pragma unroll 8
    for (int k = 0; k < D; k++) a2 += mid[k] * W2[k * D + c];
    outv[(size_t)p * D + c] = fmaxf(a2, 0.f);
}

// per node: naggb[n] = bf16(mean over copies of aggb[m]); pmusum[n] = mean of pmu[batch[m]]
__global__ __launch_bounds__(256) void k_nagg(const ushort_t* __restrict__ aggb,
                                              const float* __restrict__ pmu,
                                              const int* __restrict__ batch, const int* __restrict__ mlist,
                                              const int* __restrict__ nend, const int* __restrict__ ncnt,
                                              ushort_t* __restrict__ naggb, float* __restrict__ pmusum,
                                              int N) {
    int idx = blockIdx.x * 256 + threadIdx.x;
    int n = idx >> 5, j = idx & 31;
    if (n >= N) return;
    int kn = nend[n], c = ncnt[n], s0 = kn - c;
    f4 sa = make_float4(0.f, 0.f, 0.f, 0.f);
    f4 sp = make_float4(0.f, 0.f, 0.f, 0.f);
    for (int k = 0; k < c; k++) {
        int m = mlist[s0 + k];
        ushort4 ab = *(const ushort4*)(aggb + (size_t)m * D + j * 4);
        sa.x += b2f(ab.x); sa.y += b2f(ab.y); sa.z += b2f(ab.z); sa.w += b2f(ab.w);
        f4 pv = *((const f4*)(pmu + (size_t)batch[m] * D) + j);
        f4add(sp, pv);
    }
    float inv = 1.0f / fmaxf((float)c, 1.0f);
    ushort4 o;
    o.x = f2b(sa.x * inv); o.y = f2b(sa.y * inv); o.z = f2b(sa.z * inv); o.w = f2b(sa.w * inv);
    *(ushort4*)(naggb + (size_t)n * D + j * 4) = o;
    f4 spm = make_float4(sp.x * inv, sp.y * inv, sp.z * inv, sp.w * inv);
    *((f4*)(pmusum + (size_t)n * D) + j) = spm;
}

// hn[N,128] = naggb(bf16) @ W[l] + b[l] + pmusum, MFMA 16x16x32, 64 rows/block
__global__ __launch_bounds__(256) void k_nup(const ushort_t* __restrict__ naggb,
                                             const ushort_t* __restrict__ Wtb,
                                             const float* __restrict__ bg,
                                             const float* __restrict__ pmusum,
                                             float* __restrict__ hn, int N, int layer) {
    __shared__ ushort_t Wl[128 * 136];  // [col][k] padded
    const ushort_t* W = Wtb + (size_t)layer * D * D;
    int t = threadIdx.x;
#pragma unroll
    for (int i = 0; i < 8; i++) {
        int cid = t + i * 256;
        int col = cid >> 4, kc = (cid & 15) * 8;
        *(short8*)&Wl[col * 136 + kc] = *(const short8*)(W + col * 128 + kc);
    }
    __syncthreads();
    int w = t >> 6, lane = t & 63;
    int r16 = lane & 15, kg = lane >> 4;
    int rowbase = blockIdx.x * 64 + w * 16;
    size_t arow = (size_t)min(rowbase + r16, N - 1) * D;
    short8 a0 = *(const short8*)(naggb + arow + 0 + kg * 8);
    short8 a1 = *(const short8*)(naggb + arow + 32 + kg * 8);
    short8 a2 = *(const short8*)(naggb + arow + 64 + kg * 8);
    short8 a3 = *(const short8*)(naggb + arow + 96 + kg * 8);
    f32x4 acc[8];
#pragma unroll
    for (int c = 0; c < 8; c++) acc[c] = (f32x4){0.f, 0.f, 0.f, 0.f};
#pragma unroll
    for (int c = 0; c < 8; c++) {
        const ushort_t* wp = &Wl[(c * 16 + r16) * 136 + kg * 8];
        short8 b0 = *(const short8*)(wp + 0);
        short8 b1 = *(const short8*)(wp + 32);
        short8 b2 = *(const short8*)(wp + 64);
        short8 b3 = *(const short8*)(wp + 96);
        acc[c] = __builtin_amdgcn_mfma_f32_16x16x32_bf16(a0, b0, acc[c], 0, 0, 0);
        acc[c] = __builtin_amdgcn_mfma_f32_16x16x32_bf16(a1, b1, acc[c], 0, 0, 0);
        acc[c] = __builtin_amdgcn_mfma_f32_16x16x32_bf16(a2, b2, acc[c], 0, 0, 0);
        acc[c] = __builtin_amdgcn_mfma_f32_16x16x32_bf16(a3, b3, acc[c], 0, 0, 0);
    }
#pragma unroll
    for (int c = 0; c < 8; c++) {
        int gcol = c * 16 + r16;
        float bias = bg[layer * D + gcol];
#pragma unroll
        for (int q = 0; q < 4; q++) {
            int grow = rowbase + kg * 4 + q;
            if (grow < N)
                hn[(size_t)grow * D + gcol] = acc[c][q] + bias + pmusum[(size_t)grow * D + gcol];
        }
    }
}

extern "C" void kernel_launch(void* const* d_in, const int* in_sizes, int n_in,
                              void* d_out, int out_size, void* d_ws, size_t ws_size,
                              hipStream_t stream) {
    const float* x    = (const float*)d_in[0];
    const float* ea   = (const float*)d_in[1];
    const int* nm     = (const int*)d_in[2];
    const int* em     = (const int*)d_in[3];
    const int* cs     = (const int*)d_in[4];
    const int* batch  = (const int*)d_in[5];
    const float* Wg   = (const float*)d_in[7];
    const float* bg   = (const float*)d_in[8];
    const float* eps  = (const float*)d_in[9];
    const float* Wu   = (const float*)d_in[10];
    const float* bu   = (const float*)d_in[11];
    float* out = (float*)d_out;

    int N  = in_sizes[0] / D;
    int E  = in_sizes[1] / D;
    int M  = in_sizes[2];
    int EC = in_sizes[3];
    int P  = out_size / D;
    const int* src = cs;
    const int* dst = cs + EC;

    // workspace carve (256B aligned)
    char* base = (char*)d_ws;
    size_t off = 0;
    auto carve = [&](size_t bytes) { void* p = base + off; off += (bytes + 255) & ~(size_t)255; return p; };
    ushort_t* aggb   = (ushort_t*)carve((size_t)M * D * 2);
    ushort_t* eab    = (ushort_t*)carve((size_t)E * D * 2);
    ushort_t* Wtb    = (ushort_t*)carve((size_t)4 * D * D * 2);
    ushort_t* naggb  = (ushort_t*)carve((size_t)N * D * 2);
    float*    hn     = (float*)carve((size_t)N * D * 4);
    float*    pmusum = (float*)carve((size_t)N * D * 4);
    float*    aggP   = (float*)carve((size_t)P * D * 4);
    float*    pmu    = (float*)carve((size_t)P * D * 4);
    int* cntblk = (int*)carve((size_t)(M + N + P) * 4);
    int* ecnt = cntblk, *ncnt = cntblk + M, *pcnt = cntblk + M + N;
    int* ecur   = (int*)carve((size_t)M * 4);
    int* ncur   = (int*)carve((size_t)N * 4);
    int* nsrc   = (int*)carve((size_t)EC * 4);
    int* eem    = (int*)carve((size_t)EC * 4);
    int* mlist  = (int*)carve((size_t)M * 4);
    int* pstart = (int*)carve((size_t)P * 4);
    int* bsum   = (int*)carve(1024 * 4);
    if (ws_size < off) return;

    // ---- build (reused across layers) ----
    hipMemsetAsync(cntblk, 0, (size_t)(M + N + P) * sizeof(int), stream);
    k_hist_edges<<<(EC + 255) / 256, 256, 0, stream>>>(dst, ecnt, EC);
    k_hist_nodes<<<(M + 255) / 256, 256, 0, stream>>>(nm, batch, ncnt, pcnt, M);

    auto scan = [&](const int* in, int* outp, int n) {
        int nb = (n + 1023) / 1024;
        k_scan1<<<nb, 256, 0, stream>>>(in, outp, bsum, n);
        k_scan2<<<1, 64, 0, stream>>>(bsum, nb);
        k_scan3<<<(n + 255) / 256, 256, 0, stream>>>(outp, bsum, n);
    };
    scan(ecnt, ecur, M);
    scan(ncnt, ncur, N);
    scan(pcnt, pstart, P);

    k_scatter_edges<<<(EC + 255) / 256, 256, 0, stream>>>(dst, src, em, nm, ecur, nsrc, eem, EC);
    k_scatter_nodes<<<(M + 255) / 256, 256, 0, stream>>>(nm, ncur, mlist, M);
    k_ea2bf<<<((E * D / 8) + 255) / 256, 256, 0, stream>>>(ea, eab, E * D / 8);
    k_prepW<<<(4 * D * D + 255) / 256, 256, 0, stream>>>(Wg, Wtb, 4 * D * D);

    // ---- compute ----
    int mb = (M * 32 + 255) / 256;
    for (int i = 0; i < 4; i++) {
        const f4* hnp = (i == 0) ? (const f4*)x : (const f4*)hn;
        if (i > 0) {
            k_ptf<<<P, 128, 0, stream>>>(aggP, Wg, bg, Wu, bu, pmu, i - 1, i - 1, 1);
            k_nagg<<<(N * 32 + 255) / 256, 256, 0, stream>>>(aggb, pmu, batch, mlist,
                                                             ncur, ncnt, naggb, pmusum, N);
            k_nup<<<(N + 63) / 64, 256, 0, stream>>>(naggb, Wtb, bg, pmusum, hn, N, i - 1);
        }
        k_edge<<<mb, 256, 0, stream>>>(hnp, eab, nm, nsrc, eem, ecur, ecnt, aggb, eps, i, M);
        k_patch_agg<<<P, 256, 0, stream>>>(aggb, pstart, pcnt, aggP);
    }

    k_ptf<<<P, 128, 0, stream>>>(aggP, Wg, bg, Wu, bu, out, 3, 0, 0);
}